// Round 1
// baseline (160.588 us; speedup 1.0000x reference)
//
#include <hip/hip_runtime.h>

// Problem constants (from reference setup_inputs):
//   image:  (B=4, H=512, W=640, C=16) fp32
//   depth:  (B, H, W) fp32
//   proj:   (B, 4, 4) fp32
//   out:    (B, H, W, C) fp32
constexpr int B  = 4;
constexpr int H  = 512;
constexpr int Wd = 640;
constexpr int C  = 16;          // 4 float4 groups per pixel
constexpr int NPIX = B * H * Wd;
constexpr int NTHREADS = NPIX * (C / 4);   // one thread per (pixel, c4)

constexpr int BLOCK          = 256;
constexpr int PIX_PER_BLOCK  = BLOCK / 4;            // 64 pixels per block
constexpr int BLOCKS_PER_ROW = Wd / PIX_PER_BLOCK;   // 10 (exact)
constexpr int BLOCKS_PER_IMG = H * BLOCKS_PER_ROW;   // 5120 (exact)
static_assert(Wd % PIX_PER_BLOCK == 0, "block must tile a row exactly");
static_assert(NTHREADS % BLOCK == 0, "exact grid");

__global__ __launch_bounds__(256) void depth_project_kernel(
    const float* __restrict__ image,
    const float* __restrict__ depth,
    const float* __restrict__ proj,
    float4* __restrict__ out)
{
    const int blk = blockIdx.x;
    // b and h are block-uniform: pure SALU, and proj reads become s_loads.
    const int b   = blk / BLOCKS_PER_IMG;
    const int rem = blk % BLOCKS_PER_IMG;
    const int h   = rem / BLOCKS_PER_ROW;
    const int wb  = (rem % BLOCKS_PER_ROW) * PIX_PER_BLOCK;

    const int tix = threadIdx.x;
    const int c4  = tix & 3;        // which float4 group of the 16 channels
    const int pl  = tix >> 2;       // pixel index within block (0..63)
    const int w   = wb + pl;

    const float* P = proj + b * 16;   // uniform pointer -> scalar loads

    const int pix  = (b * H + h) * Wd + w;
    const float d  = depth[pix];
    const float x  = (float)w;
    const float y  = (float)h;

    float sx = (P[0] * x + P[1] * y + P[2])  * d + P[3];
    float sy = (P[4] * x + P[5] * y + P[6])  * d + P[7];
    float sz = (P[8] * x + P[9] * y + P[10]) * d + P[11];
    float cx = sx / sz;
    float cy = sy / sz;

    // Bilinear weights + validity (zero weight outside, clamp index for gather)
    float x0f = floorf(cx), y0f = floorf(cy);
    float wx1 = cx - x0f,   wy1 = cy - y0f;
    float wx0 = 1.0f - wx1, wy0 = 1.0f - wy1;
    int x0 = (int)x0f, y0 = (int)y0f;
    int x1 = x0 + 1,   y1 = y0 + 1;

    float vx0 = (x0 >= 0 && x0 < Wd) ? 1.0f : 0.0f;
    float vx1 = (x1 >= 0 && x1 < Wd) ? 1.0f : 0.0f;
    float vy0 = (y0 >= 0 && y0 < H)  ? 1.0f : 0.0f;
    float vy1 = (y1 >= 0 && y1 < H)  ? 1.0f : 0.0f;

    int x0c = min(max(x0, 0), Wd - 1);
    int x1c = min(max(x1, 0), Wd - 1);
    int y0c = min(max(y0, 0), H - 1);
    int y1c = min(max(y1, 0), H - 1);

    float w00 = wy0 * wx0 * vy0 * vx0;
    float w01 = wy0 * wx1 * vy0 * vx1;
    float w10 = wy1 * wx0 * vy1 * vx0;
    float w11 = wy1 * wx1 * vy1 * vx1;

    const int k00 = y0c * Wd + x0c;
    const int k01 = y0c * Wd + x1c;
    const int k10 = y1c * Wd + x0c;
    const int k11 = y1c * Wd + x1c;

    // Only load the x0 column of corners for every lane (2x16B instead of
    // 4x16B through the L1). The x1 column is recovered from the x-neighbor
    // lane (same c4, pixel p+1 sits 4 lanes over) whenever that lane's
    // clamped (y0c,x0c) equals our (y0c,x1c) -- an exact, value-based check,
    // so it is correct for ANY projection. Failing lanes (wave edge, clamps,
    // slope breaks) take a rare exec-masked fallback load (~2 lines/wave).
    const float4* img4 = (const float4*)image + b * (H * Wd * 4);
    float4 g00 = img4[k00 * 4 + c4];
    float4 g10 = img4[k10 * 4 + c4];

    const int lane = tix & 63;
    const bool has_next = (lane >> 2) != 15;   // pixel 15 of wave has no +4 lane
    const int k00n = __shfl_down(k00, 4, 64);
    const int k10n = __shfl_down(k10, 4, 64);

    float4 g01, g11;
    g01.x = __shfl_down(g00.x, 4, 64);
    g01.y = __shfl_down(g00.y, 4, 64);
    g01.z = __shfl_down(g00.z, 4, 64);
    g01.w = __shfl_down(g00.w, 4, 64);
    g11.x = __shfl_down(g10.x, 4, 64);
    g11.y = __shfl_down(g10.y, 4, 64);
    g11.z = __shfl_down(g10.z, 4, 64);
    g11.w = __shfl_down(g10.w, 4, 64);

    if (!(has_next && k00n == k01)) g01 = img4[k01 * 4 + c4];
    if (!(has_next && k10n == k11)) g11 = img4[k11 * 4 + c4];

    float4 r;
    r.x = g00.x * w00 + g01.x * w01 + g10.x * w10 + g11.x * w11;
    r.y = g00.y * w00 + g01.y * w01 + g10.y * w10 + g11.y * w11;
    r.z = g00.z * w00 + g01.z * w01 + g10.z * w10 + g11.z * w11;
    r.w = g00.w * w00 + g01.w * w01 + g10.w * w10 + g11.w * w11;

    // Perfectly coalesced: global thread id -> 16B at tid*16
    out[blk * BLOCK + tix] = r;
}

extern "C" void kernel_launch(void* const* d_in, const int* in_sizes, int n_in,
                              void* d_out, int out_size, void* d_ws, size_t ws_size,
                              hipStream_t stream) {
    const float* image = (const float*)d_in[0];
    const float* depth = (const float*)d_in[1];
    const float* proj  = (const float*)d_in[2];
    float4* out = (float4*)d_out;

    constexpr int grid = NTHREADS / BLOCK;   // 20480 blocks
    depth_project_kernel<<<grid, BLOCK, 0, stream>>>(image, depth, proj, out);
}

// Round 3
// 158.090 us; speedup vs baseline: 1.0158x; 1.0158x over previous
//
#include <hip/hip_runtime.h>

// Problem constants (from reference setup_inputs):
//   image:  (B=4, H=512, W=640, C=16) fp32
//   depth:  (B, H, W) fp32
//   proj:   (B, 4, 4) fp32
//   out:    (B, H, W, C) fp32
constexpr int B  = 4;
constexpr int H  = 512;
constexpr int Wd = 640;
constexpr int NPIX_IMG = H * Wd;                 // pixels per image
constexpr int BLOCK = 256;
constexpr int PIX_PER_BLOCK  = BLOCK / 4;        // 64 pixels per block
constexpr int BLOCKS_PER_ROW = Wd / PIX_PER_BLOCK;   // 10 (exact)
constexpr int GRID = H * BLOCKS_PER_ROW;         // 5120 blocks
static_assert(Wd % PIX_PER_BLOCK == 0, "block must tile a row exactly");

// Native vector type for nontemporal builtins (HIP_vector_type is rejected).
typedef float f32x4 __attribute__((ext_vector_type(4)));

// One thread = one (h, w, c4) position in ALL B=4 images.
// 4 independent depth->gather latency chains per thread (4x MLP) — the
// round-1 counters showed we are latency-bound (all pipes <40% busy,
// 2.2x above every throughput floor), not L1/HBM/VALU-throughput-bound.
__global__ __launch_bounds__(256) void depth_project_kernel(
    const float* __restrict__ image,
    const float* __restrict__ depth,
    const float* __restrict__ proj,
    float4* __restrict__ out)
{
    const int blk = blockIdx.x;
    // h, w-base are block-uniform: SALU math, proj reads become s_loads.
    const int h  = blk / BLOCKS_PER_ROW;
    const int wb = (blk % BLOCKS_PER_ROW) * PIX_PER_BLOCK;

    const int tix = threadIdx.x;
    const int c4  = tix & 3;        // which float4 group of the 16 channels
    const int pl  = tix >> 2;       // pixel index within block (0..63)
    const int w   = wb + pl;
    const int pix0 = h * Wd + w;    // within-image pixel index

    const float x = (float)w;
    const float y = (float)h;

    // Phase 1: all 4 depth loads in flight at once (independent chains).
    float d[B];
#pragma unroll
    for (int b = 0; b < B; ++b)
        d[b] = __builtin_nontemporal_load(depth + b * NPIX_IMG + pix0);

    // Phase 2: coords / weights / gather indices for all 4 images.
    float w00[B], w01[B], w10[B], w11[B];
    int   k00[B], k01[B], k10[B], k11[B];
#pragma unroll
    for (int b = 0; b < B; ++b) {
        const float* P = proj + b * 16;   // uniform -> scalar loads

        float sx = (P[0] * x + P[1] * y + P[2])  * d[b] + P[3];
        float sy = (P[4] * x + P[5] * y + P[6])  * d[b] + P[7];
        float sz = (P[8] * x + P[9] * y + P[10]) * d[b] + P[11];
        float cx = sx / sz;
        float cy = sy / sz;

        float x0f = floorf(cx), y0f = floorf(cy);
        float wx1 = cx - x0f,   wy1 = cy - y0f;
        float wx0 = 1.0f - wx1, wy0 = 1.0f - wy1;
        int x0 = (int)x0f, y0 = (int)y0f;
        int x1 = x0 + 1,   y1 = y0 + 1;

        float vx0 = (x0 >= 0 && x0 < Wd) ? 1.0f : 0.0f;
        float vx1 = (x1 >= 0 && x1 < Wd) ? 1.0f : 0.0f;
        float vy0 = (y0 >= 0 && y0 < H)  ? 1.0f : 0.0f;
        float vy1 = (y1 >= 0 && y1 < H)  ? 1.0f : 0.0f;

        int x0c = min(max(x0, 0), Wd - 1);
        int x1c = min(max(x1, 0), Wd - 1);
        int y0c = min(max(y0, 0), H - 1);
        int y1c = min(max(y1, 0), H - 1);

        w00[b] = wy0 * wx0 * vy0 * vx0;
        w01[b] = wy0 * wx1 * vy0 * vx1;
        w10[b] = wy1 * wx0 * vy1 * vx0;
        w11[b] = wy1 * wx1 * vy1 * vx1;

        // float4-unit offsets within image b (incl. channel group)
        const int base_b = b * (NPIX_IMG * 4);
        k00[b] = base_b + (y0c * Wd + x0c) * 4 + c4;
        k01[b] = base_b + (y0c * Wd + x1c) * 4 + c4;
        k10[b] = base_b + (y1c * Wd + x0c) * 4 + c4;
        k11[b] = base_b + (y1c * Wd + x1c) * 4 + c4;
    }

    // Phase 3: 16 independent gathers in flight; accumulate; store.
    const float4* img4 = (const float4*)image;
    float4 r[B];
#pragma unroll
    for (int b = 0; b < B; ++b) {
        float4 g00 = img4[k00[b]];
        float4 g01 = img4[k01[b]];
        float4 g10 = img4[k10[b]];
        float4 g11 = img4[k11[b]];
        float4 rr;
        rr.x = g00.x * w00[b] + g01.x * w01[b] + g10.x * w10[b] + g11.x * w11[b];
        rr.y = g00.y * w00[b] + g01.y * w01[b] + g10.y * w10[b] + g11.y * w11[b];
        rr.z = g00.z * w00[b] + g01.z * w01[b] + g10.z * w10[b] + g11.z * w11[b];
        rr.w = g00.w * w00[b] + g01.w * w01[b] + g10.w * w10[b] + g11.w * w11[b];
        r[b] = rr;
    }

    f32x4* out_v = (f32x4*)out;
#pragma unroll
    for (int b = 0; b < B; ++b) {
        // write-once stream: nontemporal to keep image resident in L2/L3
        f32x4 v = { r[b].x, r[b].y, r[b].z, r[b].w };
        __builtin_nontemporal_store(v, out_v + (b * NPIX_IMG + pix0) * 4 + c4);
    }
}

extern "C" void kernel_launch(void* const* d_in, const int* in_sizes, int n_in,
                              void* d_out, int out_size, void* d_ws, size_t ws_size,
                              hipStream_t stream) {
    const float* image = (const float*)d_in[0];
    const float* depth = (const float*)d_in[1];
    const float* proj  = (const float*)d_in[2];
    float4* out = (float4*)d_out;

    depth_project_kernel<<<GRID, BLOCK, 0, stream>>>(image, depth, proj, out);
}

// Round 4
// 155.014 us; speedup vs baseline: 1.0360x; 1.0198x over previous
//
#include <hip/hip_runtime.h>

// Problem constants (from reference setup_inputs):
//   image:  (B=4, H=512, W=640, C=16) fp32   (83.9 MB)
//   depth:  (B, H, W) fp32                    (5.2 MB)
//   proj:   (B, 4, 4) fp32
//   out:    (B, H, W, C) fp32                 (83.9 MB)
constexpr int B  = 4;
constexpr int H  = 512;
constexpr int Wd = 640;
constexpr int NPIX_IMG = H * Wd;                     // pixels per image
constexpr int BLOCK = 256;
constexpr int PIX_PER_BLOCK  = BLOCK / 4;            // 64 pixels per block
constexpr int BLOCKS_PER_ROW = Wd / PIX_PER_BLOCK;   // 10 (exact)
constexpr int BLOCKS_PER_IMG = H * BLOCKS_PER_ROW;   // 5120
constexpr int GRID = B * BLOCKS_PER_IMG;             // 20480 blocks
static_assert(Wd % PIX_PER_BLOCK == 0, "block must tile a row exactly");
static_assert(GRID * BLOCK == B * NPIX_IMG * 4, "prefetch exactly covers image");

// Native vector type for nontemporal builtins (HIP_vector_type is rejected).
typedef float f32x4 __attribute__((ext_vector_type(4)));

// Theory (round 4): the kernel is bound by ~63 MB/dispatch of HBM fetches
// issued as warp-scrambled isolated 64B lines by the gathers (~1.4 TB/s
// effective = activate-bound random reads). The harness's 335 MB fill
// between iterations evicts the image from L3 every time. Fix: stream the
// image into L2/L3 sequentially (1 extra coalesced 16B load per thread,
// block i prefetches chunk i — which is also block i's own gather region
// since the warp is near-identity), so gathers hit cache instead of
// scattering to DRAM.
__global__ __launch_bounds__(256) void depth_project_kernel(
    const float* __restrict__ image,
    const float* __restrict__ depth,
    const float* __restrict__ proj,
    float4* __restrict__ out)
{
    const int blk = blockIdx.x;
    const int tix = threadIdx.x;

    // ---- streaming prefetch: sequential, fully-coalesced, cache-allocating.
    const f32x4* img_v = (const f32x4*)image;
    f32x4 pf = img_v[blk * BLOCK + tix];

    // b, h block-uniform: SALU math, proj reads become s_loads.
    const int b   = blk / BLOCKS_PER_IMG;
    const int rem = blk % BLOCKS_PER_IMG;
    const int h   = rem / BLOCKS_PER_ROW;
    const int wb  = (rem % BLOCKS_PER_ROW) * PIX_PER_BLOCK;

    const int c4  = tix & 3;        // which float4 group of the 16 channels
    const int pl  = tix >> 2;       // pixel index within block (0..63)
    const int w   = wb + pl;
    const int pix = (b * H + h) * Wd + w;

    const float* P = proj + b * 16;   // uniform -> scalar loads
    const float x = (float)w;
    const float y = (float)h;
    const float d = depth[pix];

    float sx = (P[0] * x + P[1] * y + P[2])  * d + P[3];
    float sy = (P[4] * x + P[5] * y + P[6])  * d + P[7];
    float sz = (P[8] * x + P[9] * y + P[10]) * d + P[11];
    float cx = sx / sz;
    float cy = sy / sz;

    float x0f = floorf(cx), y0f = floorf(cy);
    float wx1 = cx - x0f,   wy1 = cy - y0f;
    float wx0 = 1.0f - wx1, wy0 = 1.0f - wy1;
    int x0 = (int)x0f, y0 = (int)y0f;
    int x1 = x0 + 1,   y1 = y0 + 1;

    float vx0 = (x0 >= 0 && x0 < Wd) ? 1.0f : 0.0f;
    float vx1 = (x1 >= 0 && x1 < Wd) ? 1.0f : 0.0f;
    float vy0 = (y0 >= 0 && y0 < H)  ? 1.0f : 0.0f;
    float vy1 = (y1 >= 0 && y1 < H)  ? 1.0f : 0.0f;

    int x0c = min(max(x0, 0), Wd - 1);
    int x1c = min(max(x1, 0), Wd - 1);
    int y0c = min(max(y0, 0), H - 1);
    int y1c = min(max(y1, 0), H - 1);

    float w00 = wy0 * wx0 * vy0 * vx0;
    float w01 = wy0 * wx1 * vy0 * vx1;
    float w10 = wy1 * wx0 * vy1 * vx0;
    float w11 = wy1 * wx1 * vy1 * vx1;

    // keep the prefetch load alive (no DCE) — value is never used otherwise
    asm volatile("" :: "v"(pf.x), "v"(pf.y), "v"(pf.z), "v"(pf.w));

    const float4* img4 = (const float4*)image;
    const int base_b = b * (NPIX_IMG * 4);   // float4 units
    float4 g00 = img4[base_b + (y0c * Wd + x0c) * 4 + c4];
    float4 g01 = img4[base_b + (y0c * Wd + x1c) * 4 + c4];
    float4 g10 = img4[base_b + (y1c * Wd + x0c) * 4 + c4];
    float4 g11 = img4[base_b + (y1c * Wd + x1c) * 4 + c4];

    f32x4 r;
    r.x = g00.x * w00 + g01.x * w01 + g10.x * w10 + g11.x * w11;
    r.y = g00.y * w00 + g01.y * w01 + g10.y * w10 + g11.y * w11;
    r.z = g00.z * w00 + g01.z * w01 + g10.z * w10 + g11.z * w11;
    r.w = g00.w * w00 + g01.w * w01 + g10.w * w10 + g11.w * w11;

    // write-once stream: nontemporal so the store doesn't evict the image
    f32x4* out_v = (f32x4*)out;
    __builtin_nontemporal_store(r, out_v + pix * 4 + c4);
}

extern "C" void kernel_launch(void* const* d_in, const int* in_sizes, int n_in,
                              void* d_out, int out_size, void* d_ws, size_t ws_size,
                              hipStream_t stream) {
    const float* image = (const float*)d_in[0];
    const float* depth = (const float*)d_in[1];
    const float* proj  = (const float*)d_in[2];
    float4* out = (float4*)d_out;

    depth_project_kernel<<<GRID, BLOCK, 0, stream>>>(image, depth, proj, out);
}